// Round 4
// baseline (238.786 us; speedup 1.0000x reference)
//
#include <hip/hip_runtime.h>

#define N_WORDS 16384
#define EMB 128
#define NROOTS 2048
#define EPS 1e-8f
#define LOG2_BOOST 0.5849625007211562f   // log2(1.5)
#define HIST_BLOCKS 64

// ws layout (bytes):
//   [0,     8192)   counts  int[2048]   (memset 0)
//   [8192,  8196)   done    int         (memset 0)
//   [8196,  8200)   denom   float       (written by last hist block)
//   [16384, 81920)  roots   int[16384]
//   [81920, ...)    g       float[2048*128]

// blocks [0,64): histogram + ticket; last block computes softmax denominator
//   (hidden under the matvec blocks, which are still running).
// blocks [64, 64+2048): one block per root, g[r] = M[r] @ e[r] + bias[r].
__global__ void k_fused(const float* __restrict__ M, const float* __restrict__ e,
                        const float* __restrict__ bias, float* __restrict__ g,
                        const int* __restrict__ wi, const int* __restrict__ rmap,
                        const float* __restrict__ w,
                        int* __restrict__ roots, int* __restrict__ counts,
                        int* __restrict__ done, float* __restrict__ denom) {
    if (blockIdx.x < HIST_BLOCKS) {
        __shared__ int amLast;
        __shared__ float sred[4];
        int n = blockIdx.x * 256 + threadIdx.x;
        int r = rmap[wi[n]];
        roots[n] = r;
        atomicAdd(&counts[r], 1);
        __threadfence();                       // release: counts/roots visible
        __syncthreads();
        if (threadIdx.x == 0) amLast = (atomicAdd(done, 1) == HIST_BLOCKS - 1);
        __syncthreads();
        if (!amLast) return;
        __threadfence();                       // acquire: see all blocks' updates
        float acc = 0.f;
#pragma unroll 8
        for (int i = threadIdx.x; i < N_WORDS; i += 256) {
            float c = (float)(counts[roots[i]] - 1);
            acc += fmaf(w[i], exp2f(c * LOG2_BOOST), EPS);
        }
#pragma unroll
        for (int off = 32; off; off >>= 1) acc += __shfl_xor(acc, off, 64);
        int wave = threadIdx.x >> 6, lane = threadIdx.x & 63;
        if (lane == 0) sred[wave] = acc;
        __syncthreads();
        if (threadIdx.x == 0) *denom = sred[0] + sred[1] + sred[2] + sred[3];
        return;
    }
    // ---- matvec: one block (256 thr) per root; 8 half-waves × 16 iters = 128 rows
    int r = blockIdx.x - HIST_BLOCKS;
    int half = threadIdx.x >> 5;               // 0..7: row group
    int lane32 = threadIdx.x & 31;             // column slice (float4)
    size_t rbase = (size_t)r << 7;
    const float4* Mr = (const float4*)(M + rbase * EMB);
    float4 ev = ((const float4*)(e + rbase))[lane32];   // loaded once, reused 16×
#pragma unroll
    for (int it = 0; it < 16; ++it) {
        int row = (it << 3) + half;
        float4 m = Mr[(row << 5) + lane32];
        float d = fmaf(m.x, ev.x, fmaf(m.y, ev.y, fmaf(m.z, ev.z, m.w * ev.w)));
#pragma unroll
        for (int off = 16; off; off >>= 1) d += __shfl_xor(d, off, 64);  // 32-lane group
        if (lane32 == 0) g[rbase + row] = d + bias[rbase + row];
    }
}

// one float4 per thread; scale by v/denom recomputed inline
__global__ void k_out(const float* __restrict__ g, const int* __restrict__ roots,
                      const int* __restrict__ counts, const float* __restrict__ w,
                      const float* __restrict__ denom, float4* __restrict__ out) {
    int idx = blockIdx.x * 256 + threadIdx.x;
    int n = idx >> 5;
    int r = roots[n];
    float c = (float)(counts[r] - 1);
    float v = fmaf(w[n], exp2f(c * LOG2_BOOST), EPS);
    float s = v / *denom;
    float4 gv = ((const float4*)(g + ((size_t)r << 7)))[idx & 31];
    gv.x *= s; gv.y *= s; gv.z *= s; gv.w *= s;
    out[idx] = gv;
}

extern "C" void kernel_launch(void* const* d_in, const int* in_sizes, int n_in,
                              void* d_out, int out_size, void* d_ws, size_t ws_size,
                              hipStream_t stream) {
    const float* emb  = (const float*)d_in[0];
    const float* M    = (const float*)d_in[1];
    const float* bias = (const float*)d_in[2];
    const float* attw = (const float*)d_in[3];
    const int*   wi   = (const int*)d_in[4];
    const int*   rmap = (const int*)d_in[5];
    float* out = (float*)d_out;

    char* ws = (char*)d_ws;
    int*   counts = (int*)(ws);
    int*   done   = (int*)(ws + 8192);
    float* denom  = (float*)(ws + 8196);
    int*   roots  = (int*)(ws + 16384);
    float* g      = (float*)(ws + 81920);

    hipMemsetAsync(ws, 0, 8200, stream);   // counts + done + denom
    k_fused<<<HIST_BLOCKS + NROOTS, 256, 0, stream>>>(M, emb, bias, g, wi, rmap, attw,
                                                      roots, counts, done, denom);
    k_out<<<N_WORDS * (EMB / 4) / 256, 256, 0, stream>>>(g, roots, counts, attw, denom, (float4*)out);
}

// Round 5
// 231.632 us; speedup vs baseline: 1.0309x; 1.0309x over previous
//
#include <hip/hip_runtime.h>

#define N_WORDS 16384
#define EMB 128
#define NROOTS 2048
#define EPS 1e-8f
#define LOG2_BOOST 0.5849625007211562f   // log2(1.5)
#define HIST_BLOCKS 64

// ws layout (bytes):
//   [0,     8192)   counts  int[2048]   (memset 0)
//   [8192,  8196)   done    int         (memset 0)
//   [8196,  8200)   denom   float       (written by last hist block)
//   [16384, 81920)  roots   int[16384]
//   [81920, ...)    g       float[2048*128]

// blocks [0,2048): one block per root, g[r] = M[r] @ e[r] + bias[r], max-ILP.
// blocks [2048, 2048+64): histogram + ticket; last computes softmax denominator
//   (overlaps still-draining matvec blocks — R2's measured-better ordering).
__global__ void k_fused(const float* __restrict__ M, const float* __restrict__ e,
                        const float* __restrict__ bias, float* __restrict__ g,
                        const int* __restrict__ wi, const int* __restrict__ rmap,
                        const float* __restrict__ w,
                        int* __restrict__ roots, int* __restrict__ counts,
                        int* __restrict__ done, float* __restrict__ denom) {
    if (blockIdx.x >= NROOTS) {
        // ---- histogram blocks ----
        __shared__ int amLast;
        __shared__ float sred[4];
        int n = (blockIdx.x - NROOTS) * 256 + threadIdx.x;
        int r = rmap[wi[n]];
        roots[n] = r;
        atomicAdd(&counts[r], 1);
        __threadfence();                       // release: counts/roots visible
        __syncthreads();
        if (threadIdx.x == 0) amLast = (atomicAdd(done, 1) == HIST_BLOCKS - 1);
        __syncthreads();
        if (!amLast) return;
        __threadfence();                       // acquire: see all blocks' updates
        float acc = 0.f;
#pragma unroll 8
        for (int i = threadIdx.x; i < N_WORDS; i += 256) {
            float c = (float)(counts[roots[i]] - 1);
            acc += fmaf(w[i], exp2f(c * LOG2_BOOST), EPS);
        }
#pragma unroll
        for (int off = 32; off; off >>= 1) acc += __shfl_xor(acc, off, 64);
        int wave = threadIdx.x >> 6, lane = threadIdx.x & 63;
        if (lane == 0) sred[wave] = acc;
        __syncthreads();
        if (threadIdx.x == 0) *denom = sred[0] + sred[1] + sred[2] + sred[3];
        return;
    }
    // ---- matvec: one block per root. Thread t owns float4 slices t+256k,
    //      k=0..15: row = (t>>5)+8k, col4 = t&31 (constant per thread).
    int r = blockIdx.x;
    int t = threadIdx.x;
    int col4 = t & 31;
    int q = t >> 5;
    size_t rbase = (size_t)r << 7;
    const float4* M4 = (const float4*)(M + rbase * EMB);
    float4 ev = ((const float4*)(e + rbase))[col4];

    float4 m[16];
#pragma unroll
    for (int k = 0; k < 16; ++k) m[k] = M4[t + (k << 8)];   // 16 independent dwordx4
    __builtin_amdgcn_sched_barrier(0);   // keep all 16 loads issued before consumers
    float acc[16];
#pragma unroll
    for (int k = 0; k < 16; ++k)
        acc[k] = fmaf(m[k].x, ev.x, fmaf(m[k].y, ev.y, fmaf(m[k].z, ev.z, m[k].w * ev.w)));
    __builtin_amdgcn_sched_barrier(0);
#pragma unroll
    for (int k = 0; k < 16; ++k) {
#pragma unroll
        for (int off = 16; off; off >>= 1) acc[k] += __shfl_xor(acc[k], off, 64);  // 32-lane group
        if (col4 == 0) {
            int row = q + (k << 3);
            g[rbase + row] = acc[k] + bias[rbase + row];
        }
    }
}

// one float4 per thread; scale by v/denom recomputed inline
__global__ void k_out(const float* __restrict__ g, const int* __restrict__ roots,
                      const int* __restrict__ counts, const float* __restrict__ w,
                      const float* __restrict__ denom, float4* __restrict__ out) {
    int idx = blockIdx.x * 256 + threadIdx.x;
    int n = idx >> 5;
    int r = roots[n];
    float c = (float)(counts[r] - 1);
    float v = fmaf(w[n], exp2f(c * LOG2_BOOST), EPS);
    float s = v / *denom;
    float4 gv = ((const float4*)(g + ((size_t)r << 7)))[idx & 31];
    gv.x *= s; gv.y *= s; gv.z *= s; gv.w *= s;
    out[idx] = gv;
}

extern "C" void kernel_launch(void* const* d_in, const int* in_sizes, int n_in,
                              void* d_out, int out_size, void* d_ws, size_t ws_size,
                              hipStream_t stream) {
    const float* emb  = (const float*)d_in[0];
    const float* M    = (const float*)d_in[1];
    const float* bias = (const float*)d_in[2];
    const float* attw = (const float*)d_in[3];
    const int*   wi   = (const int*)d_in[4];
    const int*   rmap = (const int*)d_in[5];
    float* out = (float*)d_out;

    char* ws = (char*)d_ws;
    int*   counts = (int*)(ws);
    int*   done   = (int*)(ws + 8192);
    float* denom  = (float*)(ws + 8196);
    int*   roots  = (int*)(ws + 16384);
    float* g      = (float*)(ws + 81920);

    hipMemsetAsync(ws, 0, 8200, stream);   // counts + done + denom
    k_fused<<<NROOTS + HIST_BLOCKS, 256, 0, stream>>>(M, emb, bias, g, wi, rmap, attw,
                                                      roots, counts, done, denom);
    k_out<<<N_WORDS * (EMB / 4) / 256, 256, 0, stream>>>(g, roots, counts, attw, denom, (float4*)out);
}